// Round 5
// baseline (121.669 us; speedup 1.0000x reference)
//
#include <hip/hip_runtime.h>
#include <math.h>

#define IN_DIM 8192
#define H_DIM 4096

__device__ __forceinline__ float sigmoidf_(float x) {
    return 1.0f / (1.0f + __expf(-x));
}

__device__ __forceinline__ float wave_reduce_sum(float v) {
    #pragma unroll
    for (int off = 32; off > 0; off >>= 1)
        v += __shfl_xor(v, off, 64);
    return v;
}

// Kernel 1 (uniform 16-iter waves, broadcast vector staged in LDS):
//   blocks 0..2047:    2 z-rows each; 2 waves per row (half-row each).
//                      z = relu(W1 @ x + b1)
//   blocks 2048..6143: 4 W_hh rows each (one per wave).
//                      hhp = W_hh @ h0 + b_hh + b_ih
__global__ __launch_bounds__(256) void k1_z_hh(
        const float* __restrict__ W1, const float* __restrict__ x,
        const float* __restrict__ b1,
        const float* __restrict__ W_hh, const float* __restrict__ h0,
        const float* __restrict__ b_hh, const float* __restrict__ b_ih,
        float* __restrict__ z, float* __restrict__ hhp) {
    __shared__ float4 vec[2048];   // 32 KB: x (z-part) or h0 (hh-part, 16 KB used)
    __shared__ float part[4];
    const int w = threadIdx.x >> 6;
    const int lane = threadIdx.x & 63;
    const int b = blockIdx.x;

    if (b < 2048) {
        const float4* xv = (const float4*)x;
        #pragma unroll
        for (int i = 0; i < 8; ++i)
            vec[i * 256 + threadIdx.x] = xv[i * 256 + threadIdx.x];
        __syncthreads();

        const int row  = b * 2 + (w >> 1);      // 2 rows per block
        const int half = w & 1;                 // half-row per wave
        const float4* rp = (const float4*)(W1 + (size_t)row * IN_DIM);
        float acc = 0.0f;
        #pragma unroll
        for (int it = 0; it < 16; ++it) {
            const int idx = half * 1024 + it * 64 + lane;
            float4 wv = rp[idx];
            float4 v  = vec[idx];
            acc += wv.x * v.x + wv.y * v.y + wv.z * v.z + wv.w * v.w;
        }
        acc = wave_reduce_sum(acc);
        if (lane == 0) part[w] = acc;
        __syncthreads();
        if (threadIdx.x < 2) {
            const int r = b * 2 + threadIdx.x;
            z[r] = fmaxf(part[threadIdx.x * 2] + part[threadIdx.x * 2 + 1] + b1[r], 0.0f);
        }
    } else {
        const float4* hv = (const float4*)h0;
        #pragma unroll
        for (int i = 0; i < 4; ++i)
            vec[i * 256 + threadIdx.x] = hv[i * 256 + threadIdx.x];
        __syncthreads();

        const int r = (b - 2048) * 4 + w;       // 0 .. 16383
        const float4* rp = (const float4*)(W_hh + (size_t)r * H_DIM);
        float acc = 0.0f;
        #pragma unroll
        for (int it = 0; it < 16; ++it) {
            const int idx = it * 64 + lane;
            float4 wv = rp[idx];
            float4 v  = vec[idx];
            acc += wv.x * v.x + wv.y * v.y + wv.z * v.z + wv.w * v.w;
        }
        acc = wave_reduce_sum(acc);
        if (lane == 0) hhp[r] = acc + b_hh[r] + b_ih[r];
    }
}

// Kernel 2: one block per hidden j; z staged in LDS. Wave g computes
// W_ih[j + g*4096] . z, LDS combine, thread 0 does the LSTM elementwise.
__global__ __launch_bounds__(256) void k2_ih_lstm(
        const float* __restrict__ W_ih, const float* __restrict__ z,
        const float* __restrict__ hhp, const float* __restrict__ c0,
        float* __restrict__ out_h,   // d_out + 1
        float* __restrict__ out_c,   // d_out + 1 + 4096
        float* __restrict__ h_ws) {
    __shared__ float4 vec[1024];   // 16 KB: z
    __shared__ float part[4];
    const int j = blockIdx.x;                   // 0..4095
    const int g = threadIdx.x >> 6;
    const int lane = threadIdx.x & 63;

    const float4* zv = (const float4*)z;
    #pragma unroll
    for (int i = 0; i < 4; ++i)
        vec[i * 256 + threadIdx.x] = zv[i * 256 + threadIdx.x];
    __syncthreads();

    const float4* rp = (const float4*)(W_ih + (size_t)(j + g * H_DIM) * H_DIM);
    float acc = 0.0f;
    #pragma unroll
    for (int it = 0; it < 16; ++it) {
        const int idx = it * 64 + lane;
        float4 wv = rp[idx];
        float4 v  = vec[idx];
        acc += wv.x * v.x + wv.y * v.y + wv.z * v.z + wv.w * v.w;
    }
    acc = wave_reduce_sum(acc);
    if (lane == 0) part[g] = acc;
    __syncthreads();

    if (threadIdx.x == 0) {
        const float gi = part[0] + hhp[j];
        const float gf = part[1] + hhp[j + H_DIM];
        const float gg = part[2] + hhp[j + 2 * H_DIM];
        const float go = part[3] + hhp[j + 3 * H_DIM];
        const float cn = sigmoidf_(gf) * c0[j] + sigmoidf_(gi) * tanhf(gg);
        const float hn = sigmoidf_(go) * tanhf(cn);
        out_h[j] = hn;
        out_c[j] = cn;
        h_ws[j] = hn;
    }
}

// Kernel 3: a_new = sigmoid(W3 . h + b3); lag blend; write y1 and a.
__global__ __launch_bounds__(256) void k3_head(
        const float* __restrict__ W3, const float* __restrict__ b3,
        const float* __restrict__ h_ws,
        const float* __restrict__ u, const float* __restrict__ a_pre,
        const float* __restrict__ y_pre,
        float* __restrict__ d_out) {  // y1 at [0], a at [8193]
    __shared__ float red[4];
    const int t = threadIdx.x;
    const int lane = t & 63;
    const int wid = t >> 6;

    const float4* wv = (const float4*)W3;
    const float4* hv = (const float4*)h_ws;
    float acc = 0.0f;
    #pragma unroll
    for (int it = 0; it < 4; ++it) {
        const int idx = it * 256 + t;  // 1024 float4 total
        float4 w = wv[idx];
        float4 v = hv[idx];
        acc += w.x * v.x + w.y * v.y + w.z * v.z + w.w * v.w;
    }
    acc = wave_reduce_sum(acc);
    if (lane == 0) red[wid] = acc;
    __syncthreads();
    if (t == 0) {
        const float dot = red[0] + red[1] + red[2] + red[3];
        const float a_new = sigmoidf_(dot + b3[0]);
        const float uu = u[0];
        const float a = uu * a_pre[0] + (1.0f - uu) * a_new;
        const float y1 = a * uu + (1.0f - a) * y_pre[0];
        d_out[0] = y1;
        d_out[1 + 2 * H_DIM] = a;  // index 8193
    }
}

extern "C" void kernel_launch(void* const* d_in, const int* in_sizes, int n_in,
                              void* d_out, int out_size, void* d_ws, size_t ws_size,
                              hipStream_t stream) {
    const float* x     = (const float*)d_in[0];
    const float* u     = (const float*)d_in[1];
    const float* h0    = (const float*)d_in[2];
    const float* c0    = (const float*)d_in[3];
    const float* y_pre = (const float*)d_in[4];
    const float* a_pre = (const float*)d_in[5];
    const float* W1    = (const float*)d_in[6];
    const float* b1    = (const float*)d_in[7];
    const float* W_ih  = (const float*)d_in[8];
    const float* b_ih  = (const float*)d_in[9];
    const float* W_hh  = (const float*)d_in[10];
    const float* b_hh  = (const float*)d_in[11];
    const float* W3    = (const float*)d_in[12];
    const float* b3    = (const float*)d_in[13];

    float* out = (float*)d_out;

    // Workspace layout (floats): z[4096] | hhp[16384] | h_new[4096]
    float* z   = (float*)d_ws;
    float* hhp = z + H_DIM;
    float* hws = hhp + 4 * H_DIM;

    // k1: 2048 z-blocks + 4096 hh-blocks = 6144 uniform blocks
    k1_z_hh<<<6144, 256, 0, stream>>>(W1, x, b1, W_hh, h0, b_hh, b_ih, z, hhp);

    // k2: one block per hidden j
    k2_ih_lstm<<<4096, 256, 0, stream>>>(W_ih, z, hhp, c0,
                                         out + 1, out + 1 + H_DIM, hws);

    // k3: single block
    k3_head<<<1, 256, 0, stream>>>(W3, b3, hws, u, a_pre, y_pre, out);
}

// Round 6
// 108.388 us; speedup vs baseline: 1.1225x; 1.1225x over previous
//
#include <hip/hip_runtime.h>
#include <math.h>

#define IN_DIM 8192
#define H_DIM 4096

typedef float vf4 __attribute__((ext_vector_type(4)));

__device__ __forceinline__ float sigmoidf_(float x) {
    return 1.0f / (1.0f + __expf(-x));
}

__device__ __forceinline__ float wave_reduce_sum(float v) {
    #pragma unroll
    for (int off = 32; off > 0; off >>= 1)
        v += __shfl_xor(v, off, 64);
    return v;
}

__device__ __forceinline__ vf4 nt_load(const float* p) {
    return __builtin_nontemporal_load((const vf4*)p);
}

// Kernel 1 (uniform 16-iter waves):
//   blocks 0..2047:    2 z-rows each; 2 waves per row (half-row each), LDS combine.
//                      z = relu(W1 @ x + b1)
//   blocks 2048..6143: 4 W_hh rows each (one per wave).
//                      hhp = W_hh @ h0 + b_hh + b_ih
__global__ __launch_bounds__(256) void k1_z_hh(
        const float* __restrict__ W1, const float* __restrict__ x,
        const float* __restrict__ b1,
        const float* __restrict__ W_hh, const float* __restrict__ h0,
        const float* __restrict__ b_hh, const float* __restrict__ b_ih,
        float* __restrict__ z, float* __restrict__ hhp) {
    const int w = threadIdx.x >> 6;
    const int lane = threadIdx.x & 63;
    const int b = blockIdx.x;
    __shared__ float part[4];

    if (b < 2048) {
        const int row = b * 2 + (w >> 1);       // 2 rows per block
        const int half = w & 1;                 // half-row per wave
        const float* rp = W1 + (size_t)row * IN_DIM;
        const float4* xv = (const float4*)x;
        float acc = 0.0f;
        #pragma unroll
        for (int it = 0; it < 16; ++it) {
            const int idx = half * 1024 + it * 64 + lane;
            vf4 wv = nt_load(rp + idx * 4);
            float4 v = xv[idx];
            acc += wv.x * v.x + wv.y * v.y + wv.z * v.z + wv.w * v.w;
        }
        acc = wave_reduce_sum(acc);
        if (lane == 0) part[w] = acc;
        __syncthreads();
        if (threadIdx.x < 2) {
            const int r = b * 2 + threadIdx.x;
            z[r] = fmaxf(part[threadIdx.x * 2] + part[threadIdx.x * 2 + 1] + b1[r], 0.0f);
        }
    } else {
        const int r = (b - 2048) * 4 + w;       // 0 .. 16383
        const float* rp = W_hh + (size_t)r * H_DIM;
        const float4* hv = (const float4*)h0;
        float acc = 0.0f;
        #pragma unroll
        for (int it = 0; it < 16; ++it) {
            const int idx = it * 64 + lane;
            vf4 wv = nt_load(rp + idx * 4);
            float4 v = hv[idx];
            acc += wv.x * v.x + wv.y * v.y + wv.z * v.z + wv.w * v.w;
        }
        acc = wave_reduce_sum(acc);
        if (lane == 0) hhp[r] = acc + b_hh[r] + b_ih[r];
    }
}

// Kernel 2: one block per hidden j. Wave g computes W_ih[j + g*4096] . z
// (16 iters), LDS combine, thread 0 does the LSTM elementwise and writes
// h_new / c_new (d_out) + aligned h copy (ws).
__global__ __launch_bounds__(256) void k2_ih_lstm(
        const float* __restrict__ W_ih, const float* __restrict__ z,
        const float* __restrict__ hhp, const float* __restrict__ c0,
        float* __restrict__ out_h,   // d_out + 1
        float* __restrict__ out_c,   // d_out + 1 + 4096
        float* __restrict__ h_ws) {
    const int j = blockIdx.x;                   // 0..4095
    const int g = threadIdx.x >> 6;
    const int lane = threadIdx.x & 63;
    __shared__ float part[4];

    const float* rp = W_ih + (size_t)(j + g * H_DIM) * H_DIM;
    const float4* zv = (const float4*)z;
    float acc = 0.0f;
    #pragma unroll
    for (int it = 0; it < 16; ++it) {
        const int idx = it * 64 + lane;
        vf4 wv = nt_load(rp + idx * 4);
        float4 v = zv[idx];
        acc += wv.x * v.x + wv.y * v.y + wv.z * v.z + wv.w * v.w;
    }
    acc = wave_reduce_sum(acc);
    if (lane == 0) part[g] = acc;
    __syncthreads();

    if (threadIdx.x == 0) {
        const float gi = part[0] + hhp[j];
        const float gf = part[1] + hhp[j + H_DIM];
        const float gg = part[2] + hhp[j + 2 * H_DIM];
        const float go = part[3] + hhp[j + 3 * H_DIM];
        const float cn = sigmoidf_(gf) * c0[j] + sigmoidf_(gi) * tanhf(gg);
        const float hn = sigmoidf_(go) * tanhf(cn);
        out_h[j] = hn;
        out_c[j] = cn;
        h_ws[j] = hn;
    }
}

// Kernel 3: a_new = sigmoid(W3 . h + b3); lag blend; write y1 and a.
// Single block, 256 threads.
__global__ __launch_bounds__(256) void k3_head(
        const float* __restrict__ W3, const float* __restrict__ b3,
        const float* __restrict__ h_ws,
        const float* __restrict__ u, const float* __restrict__ a_pre,
        const float* __restrict__ y_pre,
        float* __restrict__ d_out) {  // y1 at [0], a at [8193]
    __shared__ float red[4];
    const int t = threadIdx.x;
    const int lane = t & 63;
    const int wid = t >> 6;

    const float4* wv = (const float4*)W3;
    const float4* hv = (const float4*)h_ws;
    float acc = 0.0f;
    #pragma unroll
    for (int it = 0; it < 4; ++it) {
        const int idx = it * 256 + t;  // 1024 float4 total
        float4 w = wv[idx];
        float4 v = hv[idx];
        acc += w.x * v.x + w.y * v.y + w.z * v.z + w.w * v.w;
    }
    acc = wave_reduce_sum(acc);
    if (lane == 0) red[wid] = acc;
    __syncthreads();
    if (t == 0) {
        const float dot = red[0] + red[1] + red[2] + red[3];
        const float a_new = sigmoidf_(dot + b3[0]);
        const float uu = u[0];
        const float ap = a_pre[0];
        const float yp = y_pre[0];
        const float a = uu * ap + (1.0f - uu) * a_new;
        const float y1 = a * uu + (1.0f - a) * yp;
        d_out[0] = y1;
        d_out[1 + 2 * H_DIM] = a;  // index 8193
    }
}

extern "C" void kernel_launch(void* const* d_in, const int* in_sizes, int n_in,
                              void* d_out, int out_size, void* d_ws, size_t ws_size,
                              hipStream_t stream) {
    const float* x     = (const float*)d_in[0];
    const float* u     = (const float*)d_in[1];
    const float* h0    = (const float*)d_in[2];
    const float* c0    = (const float*)d_in[3];
    const float* y_pre = (const float*)d_in[4];
    const float* a_pre = (const float*)d_in[5];
    const float* W1    = (const float*)d_in[6];
    const float* b1    = (const float*)d_in[7];
    const float* W_ih  = (const float*)d_in[8];
    const float* b_ih  = (const float*)d_in[9];
    const float* W_hh  = (const float*)d_in[10];
    const float* b_hh  = (const float*)d_in[11];
    const float* W3    = (const float*)d_in[12];
    const float* b3    = (const float*)d_in[13];

    float* out = (float*)d_out;

    // Workspace layout (floats): z[4096] | hhp[16384] | h_new[4096]
    float* z   = (float*)d_ws;
    float* hhp = z + H_DIM;
    float* hws = hhp + 4 * H_DIM;

    // k1: 2048 z-blocks + 4096 hh-blocks = 6144 uniform blocks
    k1_z_hh<<<6144, 256, 0, stream>>>(W1, x, b1, W_hh, h0, b_hh, b_ih, z, hhp);

    // k2: one block per hidden j
    k2_ih_lstm<<<4096, 256, 0, stream>>>(W_ih, z, hhp, c0,
                                         out + 1, out + 1 + H_DIM, hws);

    // k3: single block
    k3_head<<<1, 256, 0, stream>>>(W3, b3, hws, u, a_pre, y_pre, out);
}